// Round 20
// baseline (75.394 us; speedup 1.0000x reference)
//
#include <hip/hip_runtime.h>
#include <hip/hip_bf16.h>
#include <math.h>

constexpr int B = 8, N = 2048, H = 512, A = 128;
constexpr float LOG2E = 1.44269504088896f;

typedef _Float16 f16x8 __attribute__((ext_vector_type(8)));
typedef float f32x4 __attribute__((ext_vector_type(4)));
typedef unsigned short ushort_t;
typedef unsigned int uint_t;

__device__ __forceinline__ f32x4 mfma16h(f16x8 a, f16x8 b, f32x4 c) {
    return __builtin_amdgcn_mfma_f32_16x16x32_f16(a, b, c, 0, 0, 0);
}
__device__ __forceinline__ ushort_t f2h(float v) {
    return __builtin_bit_cast(ushort_t, (_Float16)v);
}
__device__ __forceinline__ float h2f(ushort_t u) {
    return (float)__builtin_bit_cast(_Float16, u);
}
// async global->LDS, 16B per lane; lds base must be wave-uniform
__device__ __forceinline__ void gload16(const void* g, void* l) {
    __builtin_amdgcn_global_load_lds(
        (__attribute__((address_space(1))) void*)(g),
        (__attribute__((address_space(3))) void*)(l), 16, 0, 0);
}
// swizzled-plane byte offset for element (row within 128-block, col in [0,128))
__device__ __forceinline__ int swz_byte(int rl, int col) {
    return (rl << 8) + ((((col >> 3) << 4) | ((col & 7) << 1)) ^ ((rl & 7) << 4));
}

// ---------------- K0: transpose weights to fp16 ----------------
__global__ __launch_bounds__(256) void k0_conv(
    const float* __restrict__ Wq, const float* __restrict__ Wk,
    ushort_t* __restrict__ WqT, ushort_t* __restrict__ WkT)
{
    const int id = blockIdx.x * 256 + threadIdx.x;   // 65536 = 512*128
    const int k = id >> 7, n = id & 127;
    WqT[n * 512 + k] = f2h(Wq[id]);
    WkT[n * 512 + k] = f2h(Wk[id]);
}

// ---------------- K1: MFMA projections (1-term fp16) + gate ----------------
// Q plane stored pre-scaled by log2(e) so k2 scores are base-2 exponents.
__global__ __launch_bounds__(256, 4) void k1_mfma(
    const float* __restrict__ x,
    const ushort_t* __restrict__ WqT, const ushort_t* __restrict__ WkT,
    const float* __restrict__ bq, const float* __restrict__ bk,
    const float* __restrict__ Wv, const float* __restrict__ bv,
    ushort_t* __restrict__ QSh, ushort_t* __restrict__ KSh,
    float* __restrict__ gb)
{
    __shared__ ushort_t xh[32 * 256];                 // 16 KiB
    __shared__ float gred[2][32];
    const int t = threadIdx.x;
    const int lane = t & 63, w = t >> 6;
    const int l15 = lane & 15, l4 = lane >> 4;
    const int m0 = blockIdx.x * 32;

    f32x4 acc[2][4];
    #pragma unroll
    for (int r = 0; r < 2; ++r)
        #pragma unroll
        for (int c = 0; c < 4; ++c) acc[r][c] = {0.f, 0.f, 0.f, 0.f};

    const ushort_t* WT = (w < 2) ? WqT : WkT;
    const int colbase = (w & 1) * 64;

    for (int ck = 0; ck < 2; ++ck) {
        __syncthreads();
        #pragma unroll
        for (int it = 0; it < 8; ++it) {
            const int idx = it * 256 + t;
            const int row = idx >> 6, c4 = idx & 63;
            const float4 v = *(const float4*)(x + (size_t)(m0 + row) * H + ck * 256 + c4 * 4);
            uint2 hh;
            hh.x = (uint_t)f2h(v.x) | ((uint_t)f2h(v.y) << 16);
            hh.y = (uint_t)f2h(v.z) | ((uint_t)f2h(v.w) << 16);
            const int base = row * 512 + ((((c4 >> 1) << 4)) ^ ((row & 7) << 4)) + (c4 & 1) * 8;
            *(uint2*)((char*)xh + base) = hh;
        }
        __syncthreads();

        #pragma unroll
        for (int ks = 0; ks < 8; ++ks) {
            f16x8 ah[2], bh[4];
            const int kb = ks * 64 + l4 * 16;
            #pragma unroll
            for (int rb = 0; rb < 2; ++rb) {
                const int row = rb * 16 + l15;
                ah[rb] = *(const f16x8*)((const char*)xh + row * 512 + (kb ^ ((row & 7) << 4)));
            }
            const int kg = ck * 256 + ks * 32 + l4 * 8;
            #pragma unroll
            for (int cb = 0; cb < 4; ++cb)
                bh[cb] = *(const f16x8*)(WT + (size_t)(colbase + cb * 16 + l15) * 512 + kg);
            #pragma unroll
            for (int rb = 0; rb < 2; ++rb)
                #pragma unroll
                for (int cb = 0; cb < 4; ++cb)
                    acc[rb][cb] = mfma16h(ah[rb], bh[cb], acc[rb][cb]);
        }
    }

    const float* bias = (w < 2) ? bq : bk;
    float bb[4], wv[4];
    #pragma unroll
    for (int cb = 0; cb < 4; ++cb) {
        bb[cb] = bias[colbase + cb * 16 + l15];
        wv[cb] = Wv[colbase + cb * 16 + l15];
    }
    float p[2][4];
    #pragma unroll
    for (int rb = 0; rb < 2; ++rb)
        #pragma unroll
        for (int g = 0; g < 4; ++g) {
            float ps = 0.f;
            #pragma unroll
            for (int cb = 0; cb < 4; ++cb) {
                const float v = acc[rb][cb][g] + bb[cb];
                acc[rb][cb][g] = v;
                ps = fmaf(v, wv[cb], ps);
            }
            p[rb][g] = ps;
        }

    ushort_t* OS = (w < 2) ? QSh : KSh;
    const float osc = (w < 2) ? LOG2E : 1.0f;     // pre-scale Q by log2(e)
    #pragma unroll
    for (int rb = 0; rb < 2; ++rb) {
        #pragma unroll
        for (int cb = 0; cb < 4; ++cb) {
            const int col = colbase + cb * 16 + l15;
            #pragma unroll
            for (int g = 0; g < 4; ++g) {
                const int r = m0 + rb * 16 + l4 * 4 + g;
                const size_t blkb = (size_t)(r >> 7) * 32768;
                const int byte = swz_byte(r & 127, col);
                *(ushort_t*)((char*)OS + blkb + byte) = f2h(acc[rb][cb][g] * osc);
            }
        }
    }

    if (w < 2) {
        #pragma unroll
        for (int rb = 0; rb < 2; ++rb)
            #pragma unroll
            for (int g = 0; g < 4; ++g) {
                float v = p[rb][g];
                v += __shfl_xor(v, 1); v += __shfl_xor(v, 2);
                v += __shfl_xor(v, 4); v += __shfl_xor(v, 8);
                if (l15 == 0) gred[w][rb * 16 + l4 * 4 + g] = v;
            }
    }
    __syncthreads();
    if (t < 32) {
        const float z = gred[0][t] + gred[1][t] + bv[0];
        gb[m0 + t] = 1.f / (1.f + __expf(-z));
    }
}

// ---------------- K2s: pass 1 — Q-in-regs, single-barrier K dbuf ----------------
__global__ __launch_bounds__(256, 2) void k2s_mfma(
    const ushort_t* __restrict__ QSh, const ushort_t* __restrict__ KSh,
    float* __restrict__ lpart)
{
    __shared__ ushort_t ldsA[16384], ldsB[16384];   // 32 KiB each
    const int t = threadIdx.x;
    const int lane = t & 63, wid = t >> 6;
    const int wr = wid >> 1, wc = wid & 1;     // wr: j-half, wc: i-half
    const int l15 = lane & 15, l4 = lane >> 4;

    const int b    = blockIdx.x & 7;
    const int rest = blockIdx.x >> 3;
    const int jc   = rest >> 4;
    const int i0   = (rest & 15) << 7;
    const int base = wid * 8192;
    const int kblk0 = (b << 4) + (jc << 2);

    #define STAGE_K(jt, dst)                                                    \
    {                                                                           \
        const char* sk_ = (const char*)(KSh + (size_t)(kblk0 + (jt)) * 16384);  \
        _Pragma("unroll")                                                       \
        for (int it_ = 0; it_ < 8; ++it_) {                                     \
            const int o_ = base + it_ * 1024;                                   \
            gload16(sk_ + o_ + lane * 16, (char*)(dst) + o_);                   \
        }                                                                       \
    }

    // prologue: Q -> ldsA, K0 -> ldsB (both in flight)
    {
        const int qblk = (b << 4) + (i0 >> 7);
        const char* sq = (const char*)(QSh + (size_t)qblk * 16384);
        #pragma unroll
        for (int it = 0; it < 8; ++it) {
            const int o = base + it * 1024;
            gload16(sq + o + lane * 16, (char*)ldsA + o);
        }
        STAGE_K(0, ldsB);
    }
    __syncthreads();

    // Q fragments -> registers (then ldsA becomes the 2nd K buffer)
    f16x8 qreg[4][4];
    #pragma unroll
    for (int c = 0; c < 4; ++c) {
        const int row = wc * 64 + c * 16 + l15;
        #pragma unroll
        for (int ks = 0; ks < 4; ++ks) {
            const int kb = ks * 64 + l4 * 16;
            qreg[c][ks] = *(const f16x8*)((const char*)ldsA + (row << 8) + (kb ^ ((row & 7) << 4)));
        }
    }
    __syncthreads();          // all waves done reading Q from ldsA
    STAGE_K(1, ldsA);

    float lsum[4] = {0.f, 0.f, 0.f, 0.f};

    for (int jt = 0; jt < 4; ++jt) {
        const char* cur = (jt & 1) ? (const char*)ldsA : (const char*)ldsB;
        const int j0 = jc * 512 + jt * 128;

        f32x4 acc[4][4];
        #pragma unroll
        for (int r = 0; r < 4; ++r)
            #pragma unroll
            for (int c = 0; c < 4; ++c) acc[r][c] = {0.f, 0.f, 0.f, 0.f};

        #pragma unroll
        for (int ks = 0; ks < 4; ++ks) {
            const int kb = ks * 64 + l4 * 16;
            f16x8 ak[4];
            #pragma unroll
            for (int r = 0; r < 4; ++r) {
                const int row = wr * 64 + r * 16 + l15;
                ak[r] = *(const f16x8*)(cur + (row << 8) + (kb ^ ((row & 7) << 4)));
            }
            #pragma unroll
            for (int r = 0; r < 4; ++r)
                #pragma unroll
                for (int c = 0; c < 4; ++c)
                    acc[r][c] = mfma16h(ak[r], qreg[c][ks], acc[r][c]);
        }

        #pragma unroll
        for (int r = 0; r < 4; ++r) {
            const int jb = j0 + wr * 64 + r * 16 + l4 * 4;
            #pragma unroll
            for (int c = 0; c < 4; ++c) {
                const int i = i0 + wc * 64 + c * 16 + l15;
                #pragma unroll
                for (int g = 0; g < 4; ++g) {
                    const float e = (jb + g == i) ? 0.f : exp2f(acc[r][c][g]);
                    lsum[c] += e;
                }
            }
        }
        __syncthreads();                       // readers done + K(jt+1) landed
        if (jt < 2) STAGE_K(jt + 2, (jt & 1) ? ldsA : ldsB);   // refill freed buffer
    }

    // reduce: across l4 groups in-wave, then across wr waves via LDS
    float* lred = (float*)ldsB;
    #pragma unroll
    for (int c = 0; c < 4; ++c) {
        float v = lsum[c];
        v += __shfl_xor(v, 16); v += __shfl_xor(v, 32);
        if (lane < 16) lred[wid * 64 + c * 16 + l15] = v;
    }
    __syncthreads();
    if (t < 128) {
        const int wcb = t >> 6, cl = t & 63;
        const float l = lred[wcb * 64 + cl] + lred[(2 + wcb) * 64 + cl];
        lpart[(size_t)jc * (B * N) + (size_t)b * N + i0 + t] = l;
    }
    #undef STAGE_K
}

// ---------------- K2w: pass 2 — exp2-folded normalize, f32 out ----------------
__global__ __launch_bounds__(256, 2) void k2w_mfma(
    const ushort_t* __restrict__ QSh, const ushort_t* __restrict__ KSh,
    const float* __restrict__ gb, const float* __restrict__ lpart,
    float* __restrict__ out)
{
    __shared__ ushort_t ldsA[16384], ldsB[16384];   // 32 KiB each
    __shared__ float lscl_s[128], gvv_s[128];
    const int t = threadIdx.x;
    const int lane = t & 63, wid = t >> 6;
    const int wr = wid >> 1, wc = wid & 1;
    const int l15 = lane & 15, l4 = lane >> 4;

    const int b    = blockIdx.x & 7;
    const int rest = blockIdx.x >> 3;
    const int jc   = rest >> 4;
    const int i0   = (rest & 15) << 7;
    const size_t BN = (size_t)B * N;
    const size_t bN = (size_t)b * N;
    const int base = wid * 8192;
    const int kblk0 = (b << 4) + (jc << 2);

    #define STAGE_K(jt, dst)                                                    \
    {                                                                           \
        const char* sk_ = (const char*)(KSh + (size_t)(kblk0 + (jt)) * 16384);  \
        _Pragma("unroll")                                                       \
        for (int it_ = 0; it_ < 8; ++it_) {                                     \
            const int o_ = base + it_ * 1024;                                   \
            gload16(sk_ + o_ + lane * 16, (char*)(dst) + o_);                   \
        }                                                                       \
    }

    // prologue: Q -> ldsA, K0 -> ldsB; scale factors meanwhile
    {
        const int qblk = (b << 4) + (i0 >> 7);
        const char* sq = (const char*)(QSh + (size_t)qblk * 16384);
        #pragma unroll
        for (int it = 0; it < 8; ++it) {
            const int o = base + it * 1024;
            gload16(sq + o + lane * 16, (char*)ldsA + o);
        }
        STAGE_K(0, ldsB);
    }
    if (t < 128) {
        const size_t row = bN + i0 + t;
        const float l = lpart[row] + lpart[BN + row] + lpart[2*BN + row] + lpart[3*BN + row];
        const float g = gb[row];
        lscl_s[t] = log2f((1.f - g) / l);   // folded into exp2 argument
        gvv_s[t] = g;
    }
    __syncthreads();

    f16x8 qreg[4][4];
    #pragma unroll
    for (int c = 0; c < 4; ++c) {
        const int row = wc * 64 + c * 16 + l15;
        #pragma unroll
        for (int ks = 0; ks < 4; ++ks) {
            const int kb = ks * 64 + l4 * 16;
            qreg[c][ks] = *(const f16x8*)((const char*)ldsA + (row << 8) + (kb ^ ((row & 7) << 4)));
        }
    }
    __syncthreads();
    STAGE_K(1, ldsA);

    for (int jt = 0; jt < 4; ++jt) {
        const char* cur = (jt & 1) ? (const char*)ldsA : (const char*)ldsB;
        const int j0 = jc * 512 + jt * 128;

        f32x4 acc[4][4];
        #pragma unroll
        for (int r = 0; r < 4; ++r)
            #pragma unroll
            for (int c = 0; c < 4; ++c) acc[r][c] = {0.f, 0.f, 0.f, 0.f};

        #pragma unroll
        for (int ks = 0; ks < 4; ++ks) {
            const int kb = ks * 64 + l4 * 16;
            f16x8 ak[4];
            #pragma unroll
            for (int r = 0; r < 4; ++r) {
                const int row = wr * 64 + r * 16 + l15;
                ak[r] = *(const f16x8*)(cur + (row << 8) + (kb ^ ((row & 7) << 4)));
            }
            #pragma unroll
            for (int r = 0; r < 4; ++r)
                #pragma unroll
                for (int c = 0; c < 4; ++c)
                    acc[r][c] = mfma16h(ak[r], qreg[c][ks], acc[r][c]);
        }

        #pragma unroll
        for (int r = 0; r < 4; ++r) {
            const int jb = j0 + wr * 64 + r * 16 + l4 * 4;
            #pragma unroll
            for (int c = 0; c < 4; ++c) {
                const int li = wc * 64 + c * 16 + l15;
                const int i = i0 + li;
                const float lsc = lscl_s[li], gv = gvv_s[li];
                float4 o;
                o.x = (jb + 0 == i) ? gv : exp2f(acc[r][c][0] + lsc);
                o.y = (jb + 1 == i) ? gv : exp2f(acc[r][c][1] + lsc);
                o.z = (jb + 2 == i) ? gv : exp2f(acc[r][c][2] + lsc);
                o.w = (jb + 3 == i) ? gv : exp2f(acc[r][c][3] + lsc);
                *(float4*)(out + (bN + i) * N + jb) = o;
            }
        }
        __syncthreads();                       // readers done + K(jt+1) landed
        if (jt < 2) STAGE_K(jt + 2, (jt & 1) ? ldsA : ldsB);
    }
    #undef STAGE_K
}

extern "C" void kernel_launch(void* const* d_in, const int* in_sizes, int n_in,
                              void* d_out, int out_size, void* d_ws, size_t ws_size,
                              hipStream_t stream) {
    const float* x  = (const float*)d_in[0];
    const float* Wq = (const float*)d_in[1];
    const float* bq = (const float*)d_in[2];
    const float* Wk = (const float*)d_in[3];
    const float* bk = (const float*)d_in[4];
    const float* Wv = (const float*)d_in[5];
    const float* bv = (const float*)d_in[6];
    float* out = (float*)d_out;

    const size_t PL = (size_t)B * N * A;                 // elems / plane (4 MB)
    ushort_t* QSh = (ushort_t*)d_ws;
    ushort_t* KSh = QSh + PL;
    ushort_t* WqT = KSh + PL;
    ushort_t* WkT = WqT + H * A;
    float* gb = (float*)(WkT + H * A);                   // 64 KB
    float* lp = gb + (size_t)B * N;                      // 256 KB (4 partials)

    k0_conv<<<(H * A) / 256, 256, 0, stream>>>(Wq, Wk, WqT, WkT);
    k1_mfma<<<(B * N) / 32, 256, 0, stream>>>(x, WqT, WkT, bq, bk, Wv, bv,
                                              QSh, KSh, gb);
    k2s_mfma<<<512, 256, 0, stream>>>(QSh, KSh, lp);
    k2w_mfma<<<512, 256, 0, stream>>>(QSh, KSh, gb, lp, out);
}

// Round 21
// 69.253 us; speedup vs baseline: 1.0887x; 1.0887x over previous
//
#include <hip/hip_runtime.h>
#include <hip/hip_bf16.h>
#include <math.h>

constexpr int B = 8, N = 2048, H = 512, A = 128;
constexpr float LOG2E = 1.44269504088896f;

typedef _Float16 f16x8 __attribute__((ext_vector_type(8)));
typedef float f32x4 __attribute__((ext_vector_type(4)));
typedef unsigned short ushort_t;
typedef unsigned int uint_t;

__device__ __forceinline__ f32x4 mfma16h(f16x8 a, f16x8 b, f32x4 c) {
    return __builtin_amdgcn_mfma_f32_16x16x32_f16(a, b, c, 0, 0, 0);
}
__device__ __forceinline__ ushort_t f2h(float v) {
    return __builtin_bit_cast(ushort_t, (_Float16)v);
}
__device__ __forceinline__ float h2f(ushort_t u) {
    return (float)__builtin_bit_cast(_Float16, u);
}
__device__ __forceinline__ float fexp2(float x) {       // raw v_exp_f32
    return __builtin_amdgcn_exp2f(x);
}
// async global->LDS, 16B per lane; lds base must be wave-uniform
__device__ __forceinline__ void gload16(const void* g, void* l) {
    __builtin_amdgcn_global_load_lds(
        (__attribute__((address_space(1))) void*)(g),
        (__attribute__((address_space(3))) void*)(l), 16, 0, 0);
}
// swizzled-plane byte offset for element (row within 128-block, col in [0,128))
__device__ __forceinline__ int swz_byte(int rl, int col) {
    return (rl << 8) + ((((col >> 3) << 4) | ((col & 7) << 1)) ^ ((rl & 7) << 4));
}

// ---------------- K0: transpose weights to fp16 ----------------
__global__ __launch_bounds__(256) void k0_conv(
    const float* __restrict__ Wq, const float* __restrict__ Wk,
    ushort_t* __restrict__ WqT, ushort_t* __restrict__ WkT)
{
    const int id = blockIdx.x * 256 + threadIdx.x;   // 65536 = 512*128
    const int k = id >> 7, n = id & 127;
    WqT[n * 512 + k] = f2h(Wq[id]);
    WkT[n * 512 + k] = f2h(Wk[id]);
}

// ---------------- K1: MFMA projections (1-term fp16) + gate ----------------
// Q plane stored pre-scaled by log2(e) so k2 scores are base-2 exponents.
__global__ __launch_bounds__(256, 4) void k1_mfma(
    const float* __restrict__ x,
    const ushort_t* __restrict__ WqT, const ushort_t* __restrict__ WkT,
    const float* __restrict__ bq, const float* __restrict__ bk,
    const float* __restrict__ Wv, const float* __restrict__ bv,
    ushort_t* __restrict__ QSh, ushort_t* __restrict__ KSh,
    float* __restrict__ gb)
{
    __shared__ ushort_t xh[32 * 256];                 // 16 KiB
    __shared__ float gred[2][32];
    const int t = threadIdx.x;
    const int lane = t & 63, w = t >> 6;
    const int l15 = lane & 15, l4 = lane >> 4;
    const int m0 = blockIdx.x * 32;

    f32x4 acc[2][4];
    #pragma unroll
    for (int r = 0; r < 2; ++r)
        #pragma unroll
        for (int c = 0; c < 4; ++c) acc[r][c] = {0.f, 0.f, 0.f, 0.f};

    const ushort_t* WT = (w < 2) ? WqT : WkT;
    const int colbase = (w & 1) * 64;

    for (int ck = 0; ck < 2; ++ck) {
        __syncthreads();
        #pragma unroll
        for (int it = 0; it < 8; ++it) {
            const int idx = it * 256 + t;
            const int row = idx >> 6, c4 = idx & 63;
            const float4 v = *(const float4*)(x + (size_t)(m0 + row) * H + ck * 256 + c4 * 4);
            uint2 hh;
            hh.x = (uint_t)f2h(v.x) | ((uint_t)f2h(v.y) << 16);
            hh.y = (uint_t)f2h(v.z) | ((uint_t)f2h(v.w) << 16);
            const int base = row * 512 + ((((c4 >> 1) << 4)) ^ ((row & 7) << 4)) + (c4 & 1) * 8;
            *(uint2*)((char*)xh + base) = hh;
        }
        __syncthreads();

        #pragma unroll
        for (int ks = 0; ks < 8; ++ks) {
            f16x8 ah[2], bh[4];
            const int kb = ks * 64 + l4 * 16;
            #pragma unroll
            for (int rb = 0; rb < 2; ++rb) {
                const int row = rb * 16 + l15;
                ah[rb] = *(const f16x8*)((const char*)xh + row * 512 + (kb ^ ((row & 7) << 4)));
            }
            const int kg = ck * 256 + ks * 32 + l4 * 8;
            #pragma unroll
            for (int cb = 0; cb < 4; ++cb)
                bh[cb] = *(const f16x8*)(WT + (size_t)(colbase + cb * 16 + l15) * 512 + kg);
            #pragma unroll
            for (int rb = 0; rb < 2; ++rb)
                #pragma unroll
                for (int cb = 0; cb < 4; ++cb)
                    acc[rb][cb] = mfma16h(ah[rb], bh[cb], acc[rb][cb]);
        }
    }

    const float* bias = (w < 2) ? bq : bk;
    float bb[4], wv[4];
    #pragma unroll
    for (int cb = 0; cb < 4; ++cb) {
        bb[cb] = bias[colbase + cb * 16 + l15];
        wv[cb] = Wv[colbase + cb * 16 + l15];
    }
    float p[2][4];
    #pragma unroll
    for (int rb = 0; rb < 2; ++rb)
        #pragma unroll
        for (int g = 0; g < 4; ++g) {
            float ps = 0.f;
            #pragma unroll
            for (int cb = 0; cb < 4; ++cb) {
                const float v = acc[rb][cb][g] + bb[cb];
                acc[rb][cb][g] = v;
                ps = fmaf(v, wv[cb], ps);
            }
            p[rb][g] = ps;
        }

    ushort_t* OS = (w < 2) ? QSh : KSh;
    const float osc = (w < 2) ? LOG2E : 1.0f;     // pre-scale Q by log2(e)
    #pragma unroll
    for (int rb = 0; rb < 2; ++rb) {
        #pragma unroll
        for (int cb = 0; cb < 4; ++cb) {
            const int col = colbase + cb * 16 + l15;
            #pragma unroll
            for (int g = 0; g < 4; ++g) {
                const int r = m0 + rb * 16 + l4 * 4 + g;
                const size_t blkb = (size_t)(r >> 7) * 32768;
                const int byte = swz_byte(r & 127, col);
                *(ushort_t*)((char*)OS + blkb + byte) = f2h(acc[rb][cb][g] * osc);
            }
        }
    }

    if (w < 2) {
        #pragma unroll
        for (int rb = 0; rb < 2; ++rb)
            #pragma unroll
            for (int g = 0; g < 4; ++g) {
                float v = p[rb][g];
                v += __shfl_xor(v, 1); v += __shfl_xor(v, 2);
                v += __shfl_xor(v, 4); v += __shfl_xor(v, 8);
                if (l15 == 0) gred[w][rb * 16 + l4 * 4 + g] = v;
            }
    }
    __syncthreads();
    if (t < 32) {
        const float z = gred[0][t] + gred[1][t] + bv[0];
        gb[m0 + t] = 1.f / (1.f + __expf(-z));
    }
}

// ---------------- K2s: pass 1 — Q-in-regs, single-barrier K dbuf ----------------
__global__ __launch_bounds__(256, 2) void k2s_mfma(
    const ushort_t* __restrict__ QSh, const ushort_t* __restrict__ KSh,
    float* __restrict__ lpart)
{
    __shared__ ushort_t ldsA[16384], ldsB[16384];   // 32 KiB each
    const int t = threadIdx.x;
    const int lane = t & 63, wid = t >> 6;
    const int wr = wid >> 1, wc = wid & 1;     // wr: j-half, wc: i-half
    const int l15 = lane & 15, l4 = lane >> 4;

    const int b    = blockIdx.x & 7;
    const int rest = blockIdx.x >> 3;
    const int jc   = rest >> 4;
    const int i0   = (rest & 15) << 7;
    const int base = wid * 8192;
    const int kblk0 = (b << 4) + (jc << 2);

    #define STAGE_K(jt, dst)                                                    \
    {                                                                           \
        const char* sk_ = (const char*)(KSh + (size_t)(kblk0 + (jt)) * 16384);  \
        _Pragma("unroll")                                                       \
        for (int it_ = 0; it_ < 8; ++it_) {                                     \
            const int o_ = base + it_ * 1024;                                   \
            gload16(sk_ + o_ + lane * 16, (char*)(dst) + o_);                   \
        }                                                                       \
    }

    // prologue: Q -> ldsA, K0 -> ldsB (both in flight)
    {
        const int qblk = (b << 4) + (i0 >> 7);
        const char* sq = (const char*)(QSh + (size_t)qblk * 16384);
        #pragma unroll
        for (int it = 0; it < 8; ++it) {
            const int o = base + it * 1024;
            gload16(sq + o + lane * 16, (char*)ldsA + o);
        }
        STAGE_K(0, ldsB);
    }
    __syncthreads();

    // Q fragments -> registers (then ldsA becomes the 2nd K buffer)
    f16x8 qreg[4][4];
    #pragma unroll
    for (int c = 0; c < 4; ++c) {
        const int row = wc * 64 + c * 16 + l15;
        #pragma unroll
        for (int ks = 0; ks < 4; ++ks) {
            const int kb = ks * 64 + l4 * 16;
            qreg[c][ks] = *(const f16x8*)((const char*)ldsA + (row << 8) + (kb ^ ((row & 7) << 4)));
        }
    }
    __syncthreads();          // all waves done reading Q from ldsA
    STAGE_K(1, ldsA);

    float lsum[4] = {0.f, 0.f, 0.f, 0.f};

    for (int jt = 0; jt < 4; ++jt) {
        const char* cur = (jt & 1) ? (const char*)ldsA : (const char*)ldsB;
        const int j0 = jc * 512 + jt * 128;

        f32x4 acc[4][4];
        #pragma unroll
        for (int r = 0; r < 4; ++r)
            #pragma unroll
            for (int c = 0; c < 4; ++c) acc[r][c] = {0.f, 0.f, 0.f, 0.f};

        #pragma unroll
        for (int ks = 0; ks < 4; ++ks) {
            const int kb = ks * 64 + l4 * 16;
            f16x8 ak[4];
            #pragma unroll
            for (int r = 0; r < 4; ++r) {
                const int row = wr * 64 + r * 16 + l15;
                ak[r] = *(const f16x8*)(cur + (row << 8) + (kb ^ ((row & 7) << 4)));
            }
            #pragma unroll
            for (int r = 0; r < 4; ++r)
                #pragma unroll
                for (int c = 0; c < 4; ++c)
                    acc[r][c] = mfma16h(ak[r], qreg[c][ks], acc[r][c]);
        }

        #pragma unroll
        for (int r = 0; r < 4; ++r) {
            const int jb = j0 + wr * 64 + r * 16 + l4 * 4;
            #pragma unroll
            for (int c = 0; c < 4; ++c) {
                const int i = i0 + wc * 64 + c * 16 + l15;
                #pragma unroll
                for (int g = 0; g < 4; ++g) {
                    const float e = (jb + g == i) ? 0.f : fexp2(acc[r][c][g]);
                    lsum[c] += e;
                }
            }
        }
        __syncthreads();                       // readers done + K(jt+1) landed
        if (jt < 2) STAGE_K(jt + 2, (jt & 1) ? ldsA : ldsB);   // refill freed buffer
    }

    // reduce: across l4 groups in-wave, then across wr waves via LDS
    float* lred = (float*)ldsB;
    #pragma unroll
    for (int c = 0; c < 4; ++c) {
        float v = lsum[c];
        v += __shfl_xor(v, 16); v += __shfl_xor(v, 32);
        if (lane < 16) lred[wid * 64 + c * 16 + l15] = v;
    }
    __syncthreads();
    if (t < 128) {
        const int wcb = t >> 6, cl = t & 63;
        const float l = lred[wcb * 64 + cl] + lred[(2 + wcb) * 64 + cl];
        lpart[(size_t)jc * (B * N) + (size_t)b * N + i0 + t] = l;
    }
    #undef STAGE_K
}

// ---------------- K2w: pass 2 — exp2-folded normalize, f32 out ----------------
__global__ __launch_bounds__(256, 2) void k2w_mfma(
    const ushort_t* __restrict__ QSh, const ushort_t* __restrict__ KSh,
    const float* __restrict__ gb, const float* __restrict__ lpart,
    float* __restrict__ out)
{
    __shared__ ushort_t ldsA[16384], ldsB[16384];   // 32 KiB each
    __shared__ float lscl_s[128], gvv_s[128];
    const int t = threadIdx.x;
    const int lane = t & 63, wid = t >> 6;
    const int wr = wid >> 1, wc = wid & 1;
    const int l15 = lane & 15, l4 = lane >> 4;

    const int b    = blockIdx.x & 7;
    const int rest = blockIdx.x >> 3;
    const int jc   = rest >> 4;
    const int i0   = (rest & 15) << 7;
    const size_t BN = (size_t)B * N;
    const size_t bN = (size_t)b * N;
    const int base = wid * 8192;
    const int kblk0 = (b << 4) + (jc << 2);

    #define STAGE_K(jt, dst)                                                    \
    {                                                                           \
        const char* sk_ = (const char*)(KSh + (size_t)(kblk0 + (jt)) * 16384);  \
        _Pragma("unroll")                                                       \
        for (int it_ = 0; it_ < 8; ++it_) {                                     \
            const int o_ = base + it_ * 1024;                                   \
            gload16(sk_ + o_ + lane * 16, (char*)(dst) + o_);                   \
        }                                                                       \
    }

    // prologue: Q -> ldsA, K0 -> ldsB; scale factors meanwhile
    {
        const int qblk = (b << 4) + (i0 >> 7);
        const char* sq = (const char*)(QSh + (size_t)qblk * 16384);
        #pragma unroll
        for (int it = 0; it < 8; ++it) {
            const int o = base + it * 1024;
            gload16(sq + o + lane * 16, (char*)ldsA + o);
        }
        STAGE_K(0, ldsB);
    }
    if (t < 128) {
        const size_t row = bN + i0 + t;
        const float l = lpart[row] + lpart[BN + row] + lpart[2*BN + row] + lpart[3*BN + row];
        const float g = gb[row];
        lscl_s[t] = __logf((1.f - g) / l) * LOG2E;   // log2(sc), fast path
        gvv_s[t] = g;
    }
    __syncthreads();

    f16x8 qreg[4][4];
    #pragma unroll
    for (int c = 0; c < 4; ++c) {
        const int row = wc * 64 + c * 16 + l15;
        #pragma unroll
        for (int ks = 0; ks < 4; ++ks) {
            const int kb = ks * 64 + l4 * 16;
            qreg[c][ks] = *(const f16x8*)((const char*)ldsA + (row << 8) + (kb ^ ((row & 7) << 4)));
        }
    }
    __syncthreads();
    STAGE_K(1, ldsA);

    for (int jt = 0; jt < 4; ++jt) {
        const char* cur = (jt & 1) ? (const char*)ldsA : (const char*)ldsB;
        const int j0 = jc * 512 + jt * 128;

        f32x4 acc[4][4];
        #pragma unroll
        for (int r = 0; r < 4; ++r)
            #pragma unroll
            for (int c = 0; c < 4; ++c) acc[r][c] = {0.f, 0.f, 0.f, 0.f};

        #pragma unroll
        for (int ks = 0; ks < 4; ++ks) {
            const int kb = ks * 64 + l4 * 16;
            f16x8 ak[4];
            #pragma unroll
            for (int r = 0; r < 4; ++r) {
                const int row = wr * 64 + r * 16 + l15;
                ak[r] = *(const f16x8*)(cur + (row << 8) + (kb ^ ((row & 7) << 4)));
            }
            #pragma unroll
            for (int r = 0; r < 4; ++r)
                #pragma unroll
                for (int c = 0; c < 4; ++c)
                    acc[r][c] = mfma16h(ak[r], qreg[c][ks], acc[r][c]);
        }

        #pragma unroll
        for (int r = 0; r < 4; ++r) {
            const int jb = j0 + wr * 64 + r * 16 + l4 * 4;
            #pragma unroll
            for (int c = 0; c < 4; ++c) {
                const int li = wc * 64 + c * 16 + l15;
                const int i = i0 + li;
                const float lsc = lscl_s[li], gv = gvv_s[li];
                float4 o;
                o.x = (jb + 0 == i) ? gv : fexp2(acc[r][c][0] + lsc);
                o.y = (jb + 1 == i) ? gv : fexp2(acc[r][c][1] + lsc);
                o.z = (jb + 2 == i) ? gv : fexp2(acc[r][c][2] + lsc);
                o.w = (jb + 3 == i) ? gv : fexp2(acc[r][c][3] + lsc);
                *(float4*)(out + (bN + i) * N + jb) = o;
            }
        }
        __syncthreads();                       // readers done + K(jt+1) landed
        if (jt < 2) STAGE_K(jt + 2, (jt & 1) ? ldsA : ldsB);
    }
    #undef STAGE_K
}

extern "C" void kernel_launch(void* const* d_in, const int* in_sizes, int n_in,
                              void* d_out, int out_size, void* d_ws, size_t ws_size,
                              hipStream_t stream) {
    const float* x  = (const float*)d_in[0];
    const float* Wq = (const float*)d_in[1];
    const float* bq = (const float*)d_in[2];
    const float* Wk = (const float*)d_in[3];
    const float* bk = (const float*)d_in[4];
    const float* Wv = (const float*)d_in[5];
    const float* bv = (const float*)d_in[6];
    float* out = (float*)d_out;

    const size_t PL = (size_t)B * N * A;                 // elems / plane (4 MB)
    ushort_t* QSh = (ushort_t*)d_ws;
    ushort_t* KSh = QSh + PL;
    ushort_t* WqT = KSh + PL;
    ushort_t* WkT = WqT + H * A;
    float* gb = (float*)(WkT + H * A);                   // 64 KB
    float* lp = gb + (size_t)B * N;                      // 256 KB (4 partials)

    k0_conv<<<(H * A) / 256, 256, 0, stream>>>(Wq, Wk, WqT, WkT);
    k1_mfma<<<(B * N) / 32, 256, 0, stream>>>(x, WqT, WkT, bq, bk, Wv, bv,
                                              QSh, KSh, gb);
    k2s_mfma<<<512, 256, 0, stream>>>(QSh, KSh, lp);
    k2w_mfma<<<512, 256, 0, stream>>>(QSh, KSh, gb, lp, out);
}

// Round 24
// 69.158 us; speedup vs baseline: 1.0902x; 1.0014x over previous
//
#include <hip/hip_runtime.h>
#include <hip/hip_bf16.h>
#include <math.h>

constexpr int B = 8, N = 2048, H = 512, A = 128;
constexpr float LOG2E = 1.44269504088896f;

typedef _Float16 f16x8 __attribute__((ext_vector_type(8)));
typedef float f32x4 __attribute__((ext_vector_type(4)));
typedef unsigned short ushort_t;
typedef unsigned int uint_t;

__device__ __forceinline__ f32x4 mfma16h(f16x8 a, f16x8 b, f32x4 c) {
    return __builtin_amdgcn_mfma_f32_16x16x32_f16(a, b, c, 0, 0, 0);
}
__device__ __forceinline__ ushort_t f2h(float v) {
    return __builtin_bit_cast(ushort_t, (_Float16)v);
}
__device__ __forceinline__ float h2f(ushort_t u) {
    return (float)__builtin_bit_cast(_Float16, u);
}
__device__ __forceinline__ float fexp2(float x) {       // raw v_exp_f32
    return __builtin_amdgcn_exp2f(x);
}
// async global->LDS, 16B per lane; lds base must be wave-uniform
__device__ __forceinline__ void gload16(const void* g, void* l) {
    __builtin_amdgcn_global_load_lds(
        (__attribute__((address_space(1))) void*)(g),
        (__attribute__((address_space(3))) void*)(l), 16, 0, 0);
}
// swizzled-plane byte offset for element (row within 128-block, col in [0,128))
__device__ __forceinline__ int swz_byte(int rl, int col) {
    return (rl << 8) + ((((col >> 3) << 4) | ((col & 7) << 1)) ^ ((rl & 7) << 4));
}

// ---------------- K0: transpose weights to fp16 ----------------
__global__ __launch_bounds__(256) void k0_conv(
    const float* __restrict__ Wq, const float* __restrict__ Wk,
    ushort_t* __restrict__ WqT, ushort_t* __restrict__ WkT)
{
    const int id = blockIdx.x * 256 + threadIdx.x;   // 65536 = 512*128
    const int k = id >> 7, n = id & 127;
    WqT[n * 512 + k] = f2h(Wq[id]);
    WkT[n * 512 + k] = f2h(Wk[id]);
}

// ---------------- K1: MFMA projections (1-term fp16) + gate ----------------
// Q plane stored pre-scaled by log2(e) so k2 scores are base-2 exponents.
__global__ __launch_bounds__(256, 4) void k1_mfma(
    const float* __restrict__ x,
    const ushort_t* __restrict__ WqT, const ushort_t* __restrict__ WkT,
    const float* __restrict__ bq, const float* __restrict__ bk,
    const float* __restrict__ Wv, const float* __restrict__ bv,
    ushort_t* __restrict__ QSh, ushort_t* __restrict__ KSh,
    float* __restrict__ gb)
{
    __shared__ ushort_t xh[32 * 256];                 // 16 KiB
    __shared__ float gred[2][32];
    const int t = threadIdx.x;
    const int lane = t & 63, w = t >> 6;
    const int l15 = lane & 15, l4 = lane >> 4;
    const int m0 = blockIdx.x * 32;

    f32x4 acc[2][4];
    #pragma unroll
    for (int r = 0; r < 2; ++r)
        #pragma unroll
        for (int c = 0; c < 4; ++c) acc[r][c] = {0.f, 0.f, 0.f, 0.f};

    const ushort_t* WT = (w < 2) ? WqT : WkT;
    const int colbase = (w & 1) * 64;

    for (int ck = 0; ck < 2; ++ck) {
        __syncthreads();
        #pragma unroll
        for (int it = 0; it < 8; ++it) {
            const int idx = it * 256 + t;
            const int row = idx >> 6, c4 = idx & 63;
            const float4 v = *(const float4*)(x + (size_t)(m0 + row) * H + ck * 256 + c4 * 4);
            uint2 hh;
            hh.x = (uint_t)f2h(v.x) | ((uint_t)f2h(v.y) << 16);
            hh.y = (uint_t)f2h(v.z) | ((uint_t)f2h(v.w) << 16);
            const int base = row * 512 + ((((c4 >> 1) << 4)) ^ ((row & 7) << 4)) + (c4 & 1) * 8;
            *(uint2*)((char*)xh + base) = hh;
        }
        __syncthreads();

        #pragma unroll
        for (int ks = 0; ks < 8; ++ks) {
            f16x8 ah[2], bh[4];
            const int kb = ks * 64 + l4 * 16;
            #pragma unroll
            for (int rb = 0; rb < 2; ++rb) {
                const int row = rb * 16 + l15;
                ah[rb] = *(const f16x8*)((const char*)xh + row * 512 + (kb ^ ((row & 7) << 4)));
            }
            const int kg = ck * 256 + ks * 32 + l4 * 8;
            #pragma unroll
            for (int cb = 0; cb < 4; ++cb)
                bh[cb] = *(const f16x8*)(WT + (size_t)(colbase + cb * 16 + l15) * 512 + kg);
            #pragma unroll
            for (int rb = 0; rb < 2; ++rb)
                #pragma unroll
                for (int cb = 0; cb < 4; ++cb)
                    acc[rb][cb] = mfma16h(ah[rb], bh[cb], acc[rb][cb]);
        }
    }

    const float* bias = (w < 2) ? bq : bk;
    float bb[4], wv[4];
    #pragma unroll
    for (int cb = 0; cb < 4; ++cb) {
        bb[cb] = bias[colbase + cb * 16 + l15];
        wv[cb] = Wv[colbase + cb * 16 + l15];
    }
    float p[2][4];
    #pragma unroll
    for (int rb = 0; rb < 2; ++rb)
        #pragma unroll
        for (int g = 0; g < 4; ++g) {
            float ps = 0.f;
            #pragma unroll
            for (int cb = 0; cb < 4; ++cb) {
                const float v = acc[rb][cb][g] + bb[cb];
                acc[rb][cb][g] = v;
                ps = fmaf(v, wv[cb], ps);
            }
            p[rb][g] = ps;
        }

    ushort_t* OS = (w < 2) ? QSh : KSh;
    const float osc = (w < 2) ? LOG2E : 1.0f;     // pre-scale Q by log2(e)
    #pragma unroll
    for (int rb = 0; rb < 2; ++rb) {
        #pragma unroll
        for (int cb = 0; cb < 4; ++cb) {
            const int col = colbase + cb * 16 + l15;
            #pragma unroll
            for (int g = 0; g < 4; ++g) {
                const int r = m0 + rb * 16 + l4 * 4 + g;
                const size_t blkb = (size_t)(r >> 7) * 32768;
                const int byte = swz_byte(r & 127, col);
                *(ushort_t*)((char*)OS + blkb + byte) = f2h(acc[rb][cb][g] * osc);
            }
        }
    }

    if (w < 2) {
        #pragma unroll
        for (int rb = 0; rb < 2; ++rb)
            #pragma unroll
            for (int g = 0; g < 4; ++g) {
                float v = p[rb][g];
                v += __shfl_xor(v, 1); v += __shfl_xor(v, 2);
                v += __shfl_xor(v, 4); v += __shfl_xor(v, 8);
                if (l15 == 0) gred[w][rb * 16 + l4 * 4 + g] = v;
            }
    }
    __syncthreads();
    if (t < 32) {
        const float z = gred[0][t] + gred[1][t] + bv[0];
        gb[m0 + t] = 1.f / (1.f + __expf(-z));
    }
}

// ---------------- K2s: pass 1 — Q-in-regs, single-barrier K dbuf ----------------
__global__ __launch_bounds__(256, 2) void k2s_mfma(
    const ushort_t* __restrict__ QSh, const ushort_t* __restrict__ KSh,
    float* __restrict__ lpart)
{
    __shared__ ushort_t ldsA[16384], ldsB[16384];   // 32 KiB each
    const int t = threadIdx.x;
    const int lane = t & 63, wid = t >> 6;
    const int wr = wid >> 1, wc = wid & 1;     // wr: j-half, wc: i-half
    const int l15 = lane & 15, l4 = lane >> 4;

    const int b    = blockIdx.x & 7;
    const int rest = blockIdx.x >> 3;
    const int jc   = rest >> 4;
    const int i0   = (rest & 15) << 7;
    const int base = wid * 8192;
    const int kblk0 = (b << 4) + (jc << 2);

    #define STAGE_K(jt, dst)                                                    \
    {                                                                           \
        const char* sk_ = (const char*)(KSh + (size_t)(kblk0 + (jt)) * 16384);  \
        _Pragma("unroll")                                                       \
        for (int it_ = 0; it_ < 8; ++it_) {                                     \
            const int o_ = base + it_ * 1024;                                   \
            gload16(sk_ + o_ + lane * 16, (char*)(dst) + o_);                   \
        }                                                                       \
    }

    // prologue: Q -> ldsA, K0 -> ldsB (both in flight)
    {
        const int qblk = (b << 4) + (i0 >> 7);
        const char* sq = (const char*)(QSh + (size_t)qblk * 16384);
        #pragma unroll
        for (int it = 0; it < 8; ++it) {
            const int o = base + it * 1024;
            gload16(sq + o + lane * 16, (char*)ldsA + o);
        }
        STAGE_K(0, ldsB);
    }
    __syncthreads();

    // Q fragments -> registers (then ldsA becomes the 2nd K buffer)
    f16x8 qreg[4][4];
    #pragma unroll
    for (int c = 0; c < 4; ++c) {
        const int row = wc * 64 + c * 16 + l15;
        #pragma unroll
        for (int ks = 0; ks < 4; ++ks) {
            const int kb = ks * 64 + l4 * 16;
            qreg[c][ks] = *(const f16x8*)((const char*)ldsA + (row << 8) + (kb ^ ((row & 7) << 4)));
        }
    }
    __syncthreads();          // all waves done reading Q from ldsA
    STAGE_K(1, ldsA);

    float lsum[4] = {0.f, 0.f, 0.f, 0.f};

    for (int jt = 0; jt < 4; ++jt) {
        const char* cur = (jt & 1) ? (const char*)ldsA : (const char*)ldsB;
        const int j0 = jc * 512 + jt * 128;

        f32x4 acc[4][4];
        #pragma unroll
        for (int r = 0; r < 4; ++r)
            #pragma unroll
            for (int c = 0; c < 4; ++c) acc[r][c] = {0.f, 0.f, 0.f, 0.f};

        #pragma unroll
        for (int ks = 0; ks < 4; ++ks) {
            const int kb = ks * 64 + l4 * 16;
            f16x8 ak[4];
            #pragma unroll
            for (int r = 0; r < 4; ++r) {
                const int row = wr * 64 + r * 16 + l15;
                ak[r] = *(const f16x8*)(cur + (row << 8) + (kb ^ ((row & 7) << 4)));
            }
            #pragma unroll
            for (int r = 0; r < 4; ++r)
                #pragma unroll
                for (int c = 0; c < 4; ++c)
                    acc[r][c] = mfma16h(ak[r], qreg[c][ks], acc[r][c]);
        }

        #pragma unroll
        for (int r = 0; r < 4; ++r) {
            const int jb = j0 + wr * 64 + r * 16 + l4 * 4;
            #pragma unroll
            for (int c = 0; c < 4; ++c) {
                const int i = i0 + wc * 64 + c * 16 + l15;
                #pragma unroll
                for (int g = 0; g < 4; ++g) {
                    const float e = (jb + g == i) ? 0.f : fexp2(acc[r][c][g]);
                    lsum[c] += e;
                }
            }
        }
        __syncthreads();                       // readers done + K(jt+1) landed
        if (jt < 2) STAGE_K(jt + 2, (jt & 1) ? ldsA : ldsB);   // refill freed buffer
    }

    // reduce: across l4 groups in-wave, then across wr waves via LDS
    float* lred = (float*)ldsB;
    #pragma unroll
    for (int c = 0; c < 4; ++c) {
        float v = lsum[c];
        v += __shfl_xor(v, 16); v += __shfl_xor(v, 32);
        if (lane < 16) lred[wid * 64 + c * 16 + l15] = v;
    }
    __syncthreads();
    if (t < 128) {
        const int wcb = t >> 6, cl = t & 63;
        const float l = lred[wcb * 64 + cl] + lred[(2 + wcb) * 64 + cl];
        lpart[(size_t)jc * (B * N) + (size_t)b * N + i0 + t] = l;
    }
    #undef STAGE_K
}

// ---------------- K2w: pass 2 — exp2-folded normalize, f32 out ----------------
__global__ __launch_bounds__(256, 2) void k2w_mfma(
    const ushort_t* __restrict__ QSh, const ushort_t* __restrict__ KSh,
    const float* __restrict__ gb, const float* __restrict__ lpart,
    float* __restrict__ out)
{
    __shared__ ushort_t ldsA[16384], ldsB[16384];   // 32 KiB each
    __shared__ float lscl_s[128], gvv_s[128];
    const int t = threadIdx.x;
    const int lane = t & 63, wid = t >> 6;
    const int wr = wid >> 1, wc = wid & 1;
    const int l15 = lane & 15, l4 = lane >> 4;

    const int b    = blockIdx.x & 7;
    const int rest = blockIdx.x >> 3;
    const int jc   = rest >> 4;
    const int i0   = (rest & 15) << 7;
    const size_t BN = (size_t)B * N;
    const size_t bN = (size_t)b * N;
    const int base = wid * 8192;
    const int kblk0 = (b << 4) + (jc << 2);

    #define STAGE_K(jt, dst)                                                    \
    {                                                                           \
        const char* sk_ = (const char*)(KSh + (size_t)(kblk0 + (jt)) * 16384);  \
        _Pragma("unroll")                                                       \
        for (int it_ = 0; it_ < 8; ++it_) {                                     \
            const int o_ = base + it_ * 1024;                                   \
            gload16(sk_ + o_ + lane * 16, (char*)(dst) + o_);                   \
        }                                                                       \
    }

    // prologue: Q -> ldsA, K0 -> ldsB; scale factors meanwhile
    {
        const int qblk = (b << 4) + (i0 >> 7);
        const char* sq = (const char*)(QSh + (size_t)qblk * 16384);
        #pragma unroll
        for (int it = 0; it < 8; ++it) {
            const int o = base + it * 1024;
            gload16(sq + o + lane * 16, (char*)ldsA + o);
        }
        STAGE_K(0, ldsB);
    }
    if (t < 128) {
        const size_t row = bN + i0 + t;
        const float l = lpart[row] + lpart[BN + row] + lpart[2*BN + row] + lpart[3*BN + row];
        const float g = gb[row];
        lscl_s[t] = __logf((1.f - g) / l) * LOG2E;   // log2(sc), fast path
        gvv_s[t] = g;
    }
    __syncthreads();

    f16x8 qreg[4][4];
    #pragma unroll
    for (int c = 0; c < 4; ++c) {
        const int row = wc * 64 + c * 16 + l15;
        #pragma unroll
        for (int ks = 0; ks < 4; ++ks) {
            const int kb = ks * 64 + l4 * 16;
            qreg[c][ks] = *(const f16x8*)((const char*)ldsA + (row << 8) + (kb ^ ((row & 7) << 4)));
        }
    }
    __syncthreads();
    STAGE_K(1, ldsA);

    for (int jt = 0; jt < 4; ++jt) {
        const char* cur = (jt & 1) ? (const char*)ldsA : (const char*)ldsB;
        const int j0 = jc * 512 + jt * 128;

        f32x4 acc[4][4];
        #pragma unroll
        for (int r = 0; r < 4; ++r)
            #pragma unroll
            for (int c = 0; c < 4; ++c) acc[r][c] = {0.f, 0.f, 0.f, 0.f};

        #pragma unroll
        for (int ks = 0; ks < 4; ++ks) {
            const int kb = ks * 64 + l4 * 16;
            f16x8 ak[4];
            #pragma unroll
            for (int r = 0; r < 4; ++r) {
                const int row = wr * 64 + r * 16 + l15;
                ak[r] = *(const f16x8*)(cur + (row << 8) + (kb ^ ((row & 7) << 4)));
            }
            #pragma unroll
            for (int r = 0; r < 4; ++r)
                #pragma unroll
                for (int c = 0; c < 4; ++c)
                    acc[r][c] = mfma16h(ak[r], qreg[c][ks], acc[r][c]);
        }

        #pragma unroll
        for (int r = 0; r < 4; ++r) {
            const int jb = j0 + wr * 64 + r * 16 + l4 * 4;
            #pragma unroll
            for (int c = 0; c < 4; ++c) {
                const int li = wc * 64 + c * 16 + l15;
                const int i = i0 + li;
                const float lsc = lscl_s[li], gv = gvv_s[li];
                float4 o;
                o.x = (jb + 0 == i) ? gv : fexp2(acc[r][c][0] + lsc);
                o.y = (jb + 1 == i) ? gv : fexp2(acc[r][c][1] + lsc);
                o.z = (jb + 2 == i) ? gv : fexp2(acc[r][c][2] + lsc);
                o.w = (jb + 3 == i) ? gv : fexp2(acc[r][c][3] + lsc);
                *(float4*)(out + (bN + i) * N + jb) = o;
            }
        }
        __syncthreads();                       // readers done + K(jt+1) landed
        if (jt < 2) STAGE_K(jt + 2, (jt & 1) ? ldsA : ldsB);
    }
    #undef STAGE_K
}

extern "C" void kernel_launch(void* const* d_in, const int* in_sizes, int n_in,
                              void* d_out, int out_size, void* d_ws, size_t ws_size,
                              hipStream_t stream) {
    const float* x  = (const float*)d_in[0];
    const float* Wq = (const float*)d_in[1];
    const float* bq = (const float*)d_in[2];
    const float* Wk = (const float*)d_in[3];
    const float* bk = (const float*)d_in[4];
    const float* Wv = (const float*)d_in[5];
    const float* bv = (const float*)d_in[6];
    float* out = (float*)d_out;

    const size_t PL = (size_t)B * N * A;                 // elems / plane (4 MB)
    ushort_t* QSh = (ushort_t*)d_ws;
    ushort_t* KSh = QSh + PL;
    ushort_t* WqT = KSh + PL;
    ushort_t* WkT = WqT + H * A;
    float* gb = (float*)(WkT + H * A);                   // 64 KB
    float* lp = gb + (size_t)B * N;                      // 256 KB (4 partials)

    k0_conv<<<(H * A) / 256, 256, 0, stream>>>(Wq, Wk, WqT, WkT);
    k1_mfma<<<(B * N) / 32, 256, 0, stream>>>(x, WqT, WkT, bq, bk, Wv, bv,
                                              QSh, KSh, gb);
    k2s_mfma<<<512, 256, 0, stream>>>(QSh, KSh, lp);
    k2w_mfma<<<512, 256, 0, stream>>>(QSh, KSh, gb, lp, out);
}